// Round 5
// baseline (64.149 us; speedup 1.0000x reference)
//
#include <hip/hip_runtime.h>
#include <hip/hip_bf16.h>

#define IN 8192
#define OUT 8192

typedef __bf16 bf16x8 __attribute__((ext_vector_type(8)));
typedef float f32x4 __attribute__((ext_vector_type(4)));
typedef unsigned short u16;
typedef unsigned int u32;
typedef u32 u32x4 __attribute__((ext_vector_type(4)));

#define MFMA(a, b, c) __builtin_amdgcn_mfma_f32_16x16x32_bf16(a, b, c, 0, 0, 0)

static __device__ __forceinline__ u16 f2bf(float v) {
    __hip_bfloat16 h = __float2bfloat16(v);
    return __builtin_bit_cast(u16, h);
}
static __device__ __forceinline__ float bf2f(u16 h) {
    union { u32 u; float f; } cv; cv.u = ((u32)h) << 16; return cv.f;
}
static __device__ __forceinline__ void split_hl(float v, u16& hi, u16& lo) {
    hi = f2bf(v);
    lo = f2bf(v - bf2f(hi));
}
static __device__ __forceinline__ bf16x8 ld8(const u16* p) {
    return *reinterpret_cast<const bf16x8*>(p);
}

// ================= pre: butterfly-in + scatter to bf16 xt + S[b]  (round-3 form) =================
__global__ __launch_bounds__(1024)
void pre_kernel(const float* __restrict__ x, const float* __restrict__ shw,
                const int* __restrict__ vinp, const int* __restrict__ voutp,
                const float* __restrict__ v1, const float* __restrict__ v2,
                u16* __restrict__ xt, float* __restrict__ S) {
    __shared__ alignas(16) u16 sV1[2][64 * 72];     // v1 hi/lo, [i][j] stride 72
    __shared__ alignas(16) u16 sXb[2][128 * 72];    // X^T [n][j] stride 72; reused as T [i][k] stride 136
    __shared__ alignas(16) u16 sV2[2][128 * 136];   // v2 [l][k] stride 136
    __shared__ float sred[16];
    const int tid = threadIdx.x, b = blockIdx.x;
    const int lane = tid & 63, w = tid >> 6;
    const int l15 = lane & 15, l4 = lane >> 4;

    #pragma unroll
    for (int it = 0; it < 4; ++it) {                // v1: 4096
        int e = tid + it * 1024;
        u16 h, l; split_hl(v1[e], h, l);
        int idx = (e >> 6) * 72 + (e & 63);
        sV1[0][idx] = h; sV1[1][idx] = l;
    }
    #pragma unroll
    for (int it = 0; it < 16; ++it) {               // v2: 16384, natural [l][k]
        int e = tid + it * 1024;
        u16 h, l; split_hl(v2[e], h, l);
        int idx = (e >> 7) * 136 + (e & 127);
        sV2[0][idx] = h; sV2[1][idx] = l;
    }
    int qidx[8];
    #pragma unroll
    for (int it = 0; it < 8; ++it) qidx[it] = vinp[tid + it * 1024];
    #pragma unroll
    for (int it = 0; it < 8; ++it) {                // X gather, store transposed [n][j]
        int q = qidx[it];
        float v = x[b * IN + q] / shw[q];
        u16 h, l; split_hl(v, h, l);
        int e = tid + it * 1024;
        int idx = (e & 127) * 72 + (e >> 7);
        sXb[0][idx] = h; sXb[1][idx] = l;
    }
    __syncthreads();

    // stage1: T = v1 @ X  (M=64,N=128,K=64). wave: n-tile nt, m-half mh.
    const int nt = w & 7, mh = w >> 3;
    f32x4 acc0 = {0.f, 0.f, 0.f, 0.f}, acc1 = {0.f, 0.f, 0.f, 0.f};
    #pragma unroll
    for (int ks = 0; ks < 2; ++ks) {
        int boff = (nt * 16 + l15) * 72 + ks * 32 + l4 * 8;
        bf16x8 bh = ld8(&sXb[0][boff]), bl = ld8(&sXb[1][boff]);
        int a0 = (mh * 32 + l15) * 72 + ks * 32 + l4 * 8;
        int a1 = a0 + 16 * 72;
        bf16x8 ah0 = ld8(&sV1[0][a0]), al0 = ld8(&sV1[1][a0]);
        bf16x8 ah1 = ld8(&sV1[0][a1]), al1 = ld8(&sV1[1][a1]);
        acc0 = MFMA(ah0, bh, acc0); acc0 = MFMA(ah0, bl, acc0); acc0 = MFMA(al0, bh, acc0);
        acc1 = MFMA(ah1, bh, acc1); acc1 = MFMA(ah1, bl, acc1); acc1 = MFMA(al1, bh, acc1);
    }
    __syncthreads();                                // all waves done reading sXb
    u16* Thi = sXb[0]; u16* Tlo = sXb[1];           // T [i][k] stride 136
    #pragma unroll
    for (int m = 0; m < 2; ++m) {
        f32x4 a = m ? acc1 : acc0;
        #pragma unroll
        for (int r = 0; r < 4; ++r) {
            int i = mh * 32 + m * 16 + l4 * 4 + r;
            u16 h, l; split_hl(a[r], h, l);
            Thi[i * 136 + nt * 16 + l15] = h;
            Tlo[i * 136 + nt * 16 + l15] = l;
        }
    }
    __syncthreads();

    // stage2: Z = T @ v2^T  (M=64,N=128,K=128)
    f32x4 z0 = {0.f, 0.f, 0.f, 0.f}, z1 = {0.f, 0.f, 0.f, 0.f};
    #pragma unroll
    for (int ks = 0; ks < 4; ++ks) {
        int boff = (nt * 16 + l15) * 136 + ks * 32 + l4 * 8;
        bf16x8 bh = ld8(&sV2[0][boff]), bl = ld8(&sV2[1][boff]);
        int a0 = (mh * 32 + l15) * 136 + ks * 32 + l4 * 8;
        int a1 = a0 + 16 * 136;
        bf16x8 ah0 = ld8(&Thi[a0]), al0 = ld8(&Tlo[a0]);
        bf16x8 ah1 = ld8(&Thi[a1]), al1 = ld8(&Tlo[a1]);
        z0 = MFMA(ah0, bh, z0); z0 = MFMA(ah0, bl, z0); z0 = MFMA(al0, bh, z0);
        z1 = MFMA(ah1, bh, z1); z1 = MFMA(ah1, bl, z1); z1 = MFMA(al1, bh, z1);
    }
    __syncthreads();
    u16* Zl = &sV1[0][0];                           // 8192 u16, reuse v1 region
    #pragma unroll
    for (int m = 0; m < 2; ++m) {
        f32x4 zz = m ? z1 : z0;
        #pragma unroll
        for (int r = 0; r < 4; ++r) {
            int i = mh * 32 + m * 16 + l4 * 4 + r;
            Zl[i * 128 + nt * 16 + l15] = f2bf(zz[r]);
        }
    }
    __syncthreads();
    float ssum = 0.f;
    #pragma unroll
    for (int it = 0; it < 8; ++it) {
        int p = tid + it * 1024;
        u16 zb = Zl[voutp[p]];
        xt[(size_t)b * IN + p] = zb;
        ssum += bf2f(zb);
    }
    #pragma unroll
    for (int off = 32; off; off >>= 1) ssum += __shfl_down(ssum, off, 64);
    if (lane == 0) sred[w] = ssum;
    __syncthreads();
    if (tid == 0) {
        float t = 0.f;
        #pragma unroll
        for (int i = 0; i < 16; ++i) t += sred[i];
        S[b] = t;
    }
}

// ================= qgemm v2: LDS-staged B-slab, saturating HBM =================
// block (bx, by): o-range [bx*64, +64), k-plane [by*2048, +2048).
// 8 waves = 4 o-groups x 2 k-halves; k-halves reduced in-block; G[4][16][8192].
__global__ __launch_bounds__(512)
void qgemm_kernel(const int* __restrict__ qw, const u16* __restrict__ xt,
                  float* __restrict__ G) {
    __shared__ alignas(16) u32 sB[256 * 72];        // 72 KiB, row stride 72 u32
    const int tid = threadIdx.x;
    const int lane = tid & 63, w = tid >> 6;
    const int l15 = lane & 15, l4 = lane >> 4;
    const int o0 = blockIdx.x * 64;
    const int k0 = blockIdx.y * 2048;
    // stage B-slab: 256 rows x 64 u32, coalesced dwordx4 (256 B contiguous per row)
    #pragma unroll
    for (int i = 0; i < 8; ++i) {
        int idx = i * 512 + tid;                    // 0..4095
        int r = idx >> 4;                           // 0..255
        int c4 = (idx & 15) * 4;                    // 0..60
        u32x4 v = *reinterpret_cast<const u32x4*>(&qw[(size_t)(k0 / 8 + r) * OUT + o0 + c4]);
        *reinterpret_cast<u32x4*>(&sB[r * 72 + c4]) = v;
    }
    __syncthreads();
    const int og = w & 3, kh = w >> 2;              // o-group, k-half
    const int o = o0 + og * 16 + l15;
    const u16* ap = xt + (size_t)l15 * IN + k0 + kh * 1024 + l4 * 8;
    const u32* bp = sB + (size_t)(kh * 128 + l4) * 72 + og * 16 + l15;
    f32x4 acc = {0.f, 0.f, 0.f, 0.f};
    #pragma unroll 8
    for (int kt = 0; kt < 32; ++kt) {
        u32 q = bp[kt * 4 * 72];
        bf16x8 a = ld8(ap + kt * 32);
        u32 ev = q & 0x0F0F0F0Fu, od = (q >> 4) & 0x0F0F0F0Fu;
        float f0, f1, f2, f3, f4, f5, f6, f7;
        asm("v_cvt_f32_ubyte0 %0, %1" : "=v"(f0) : "v"(ev));
        asm("v_cvt_f32_ubyte0 %0, %1" : "=v"(f1) : "v"(od));
        asm("v_cvt_f32_ubyte1 %0, %1" : "=v"(f2) : "v"(ev));
        asm("v_cvt_f32_ubyte1 %0, %1" : "=v"(f3) : "v"(od));
        asm("v_cvt_f32_ubyte2 %0, %1" : "=v"(f4) : "v"(ev));
        asm("v_cvt_f32_ubyte2 %0, %1" : "=v"(f5) : "v"(od));
        asm("v_cvt_f32_ubyte3 %0, %1" : "=v"(f6) : "v"(ev));
        asm("v_cvt_f32_ubyte3 %0, %1" : "=v"(f7) : "v"(od));
        u32 p0, p1, p2, p3;
        asm("v_cvt_pk_bf16_f32 %0, %1, %2" : "=v"(p0) : "v"(f0), "v"(f1));
        asm("v_cvt_pk_bf16_f32 %0, %1, %2" : "=v"(p1) : "v"(f2), "v"(f3));
        asm("v_cvt_pk_bf16_f32 %0, %1, %2" : "=v"(p2) : "v"(f4), "v"(f5));
        asm("v_cvt_pk_bf16_f32 %0, %1, %2" : "=v"(p3) : "v"(f6), "v"(f7));
        u32x4 pk = {p0, p1, p2, p3};
        acc = MFMA(a, __builtin_bit_cast(bf16x8, pk), acc);
    }
    __syncthreads();                                // done reading sB
    // reduce kh=1 into kh=0 via LDS overlay (deterministic order)
    float* red = reinterpret_cast<float*>(sB);      // 4 KiB used: [4 og][256]
    if (kh == 1) {
        *reinterpret_cast<f32x4*>(red + og * 256 + lane * 4) = acc;
    }
    __syncthreads();
    if (kh == 0) {
        f32x4 v = *reinterpret_cast<f32x4*>(red + og * 256 + lane * 4);
        acc[0] += v[0]; acc[1] += v[1]; acc[2] += v[2]; acc[3] += v[3];
        float* g = G + ((size_t)blockIdx.y * 16 + l4 * 4) * OUT + o;
        #pragma unroll
        for (int r = 0; r < 4; ++r) g[(size_t)r * OUT] = acc[r];
    }
}

// ================= post: plane-reduce + scale/offset + butterfly-out + bias  (round-3 form) =================
__global__ __launch_bounds__(1024)
void post_kernel(const float* __restrict__ G, const float* __restrict__ S,
                 const int* __restrict__ uoutp, const int* __restrict__ uinp,
                 const float* __restrict__ scale, const float* __restrict__ u1,
                 const float* __restrict__ u2, const float* __restrict__ bias,
                 float* __restrict__ out) {
    __shared__ alignas(16) u16 sU1[2][64 * 72];     // u1^T [i][j] stride 72
    __shared__ alignas(16) u16 sOG[2][128 * 72];    // og^T [n][j] stride 72; reused as t2 [i][k] stride 136
    __shared__ alignas(16) u16 sU2[2][128 * 136];   // u2^T [l][k] stride 136; reused as Zp f32[8192]
    const int tid = threadIdx.x, b = blockIdx.x;
    const int lane = tid & 63, w = tid >> 6;
    const int l15 = lane & 15, l4 = lane >> 4;
    const float Sb = S[b];

    #pragma unroll
    for (int it = 0; it < 4; ++it) {                // u1^T: u1[j*64+i] -> [i][j]
        int e = tid + it * 1024;
        u16 h, l; split_hl(u1[e], h, l);
        int idx = (e & 63) * 72 + (e >> 6);
        sU1[0][idx] = h; sU1[1][idx] = l;
    }
    #pragma unroll
    for (int it = 0; it < 16; ++it) {               // u2^T: u2[k*128+l] -> [l][k]
        int e = tid + it * 1024;
        u16 h, l; split_hl(u2[e], h, l);
        int idx = (e & 127) * 136 + (e >> 7);
        sU2[0][idx] = h; sU2[1][idx] = l;
    }
    int oo[8];
    #pragma unroll
    for (int it = 0; it < 8; ++it) oo[it] = uoutp[tid + it * 1024];
    #pragma unroll
    for (int it = 0; it < 8; ++it) {
        int o = oo[it];
        float gs = G[(size_t)b * OUT + o] + G[(size_t)(16 + b) * OUT + o]
                 + G[(size_t)(32 + b) * OUT + o] + G[(size_t)(48 + b) * OUT + o];
        float v = scale[o] * (gs * (2.0f / 15.0f) - Sb);
        u16 h, l; split_hl(v, h, l);
        int e = tid + it * 1024;
        int idx = (e & 127) * 72 + (e >> 7);        // og^T [n][j]
        sOG[0][idx] = h; sOG[1][idx] = l;
    }
    __syncthreads();

    // stage1: t2 = u1^T @ og  (M=64,N=128,K=64)
    const int nt = w & 7, mh = w >> 3;
    f32x4 acc0 = {0.f, 0.f, 0.f, 0.f}, acc1 = {0.f, 0.f, 0.f, 0.f};
    #pragma unroll
    for (int ks = 0; ks < 2; ++ks) {
        int boff = (nt * 16 + l15) * 72 + ks * 32 + l4 * 8;
        bf16x8 bh = ld8(&sOG[0][boff]), bl = ld8(&sOG[1][boff]);
        int a0 = (mh * 32 + l15) * 72 + ks * 32 + l4 * 8;
        int a1 = a0 + 16 * 72;
        bf16x8 ah0 = ld8(&sU1[0][a0]), al0 = ld8(&sU1[1][a0]);
        bf16x8 ah1 = ld8(&sU1[0][a1]), al1 = ld8(&sU1[1][a1]);
        acc0 = MFMA(ah0, bh, acc0); acc0 = MFMA(ah0, bl, acc0); acc0 = MFMA(al0, bh, acc0);
        acc1 = MFMA(ah1, bh, acc1); acc1 = MFMA(ah1, bl, acc1); acc1 = MFMA(al1, bh, acc1);
    }
    __syncthreads();
    u16* Thi = sOG[0]; u16* Tlo = sOG[1];           // t2 [i][k] stride 136
    #pragma unroll
    for (int m = 0; m < 2; ++m) {
        f32x4 a = m ? acc1 : acc0;
        #pragma unroll
        for (int r = 0; r < 4; ++r) {
            int i = mh * 32 + m * 16 + l4 * 4 + r;
            u16 h, l; split_hl(a[r], h, l);
            Thi[i * 136 + nt * 16 + l15] = h;
            Tlo[i * 136 + nt * 16 + l15] = l;
        }
    }
    __syncthreads();

    // stage2: Zp = t2 @ u2  (M=64,N=128,K=128)
    f32x4 z0 = {0.f, 0.f, 0.f, 0.f}, z1 = {0.f, 0.f, 0.f, 0.f};
    #pragma unroll
    for (int ks = 0; ks < 4; ++ks) {
        int boff = (nt * 16 + l15) * 136 + ks * 32 + l4 * 8;
        bf16x8 bh = ld8(&sU2[0][boff]), bl = ld8(&sU2[1][boff]);
        int a0 = (mh * 32 + l15) * 136 + ks * 32 + l4 * 8;
        int a1 = a0 + 16 * 136;
        bf16x8 ah0 = ld8(&Thi[a0]), al0 = ld8(&Tlo[a0]);
        bf16x8 ah1 = ld8(&Thi[a1]), al1 = ld8(&Tlo[a1]);
        z0 = MFMA(ah0, bh, z0); z0 = MFMA(ah0, bl, z0); z0 = MFMA(al0, bh, z0);
        z1 = MFMA(ah1, bh, z1); z1 = MFMA(ah1, bl, z1); z1 = MFMA(al1, bh, z1);
    }
    __syncthreads();                                // all waves done reading sU2
    float* Zp = reinterpret_cast<float*>(&sU2[0][0]);
    #pragma unroll
    for (int m = 0; m < 2; ++m) {
        f32x4 zz = m ? z1 : z0;
        #pragma unroll
        for (int r = 0; r < 4; ++r) {
            int i = mh * 32 + m * 16 + l4 * 4 + r;
            Zp[i * 128 + nt * 16 + l15] = zz[r];
        }
    }
    __syncthreads();
    #pragma unroll
    for (int it = 0; it < 8; ++it) {
        int p = tid + it * 1024;
        out[(size_t)b * OUT + p] = Zp[uinp[p]] + bias[p];
    }
}

extern "C" void kernel_launch(void* const* d_in, const int* in_sizes, int n_in,
                              void* d_out, int out_size, void* d_ws, size_t ws_size,
                              hipStream_t stream) {
    const float* x     = (const float*)d_in[0];
    const int*   qw    = (const int*)d_in[1];
    const float* scale = (const float*)d_in[2];
    const float* shw   = (const float*)d_in[3];
    const float* v1    = (const float*)d_in[4];
    const float* v2    = (const float*)d_in[5];
    const float* u1    = (const float*)d_in[6];
    const float* u2    = (const float*)d_in[7];
    const float* bias  = (const float*)d_in[8];
    const int* vinp  = (const int*)d_in[9];
    const int* voutp = (const int*)d_in[10];
    const int* uinp  = (const int*)d_in[11];
    const int* uoutp = (const int*)d_in[12];
    float* out = (float*)d_out;

    char* ws = (char*)d_ws;
    u16*   xt = (u16*)ws;                           // 256 KiB  [16][8192] bf16
    float* G  = (float*)(ws + (256 << 10));         // 2 MiB    [4][16][8192] f32
    float* S  = (float*)(ws + (2304 << 10));        // 64 B     [16] f32

    pre_kernel<<<16, 1024, 0, stream>>>(x, shw, vinp, voutp, v1, v2, xt, S);
    qgemm_kernel<<<dim3(128, 4), 512, 0, stream>>>(qw, xt, G);
    post_kernel<<<16, 1024, 0, stream>>>(G, S, uoutp, uinp, scale, u1, u2, bias, out);
}